// Round 5
// baseline (216.881 us; speedup 1.0000x reference)
//
#include <hip/hip_runtime.h>
#include <float.h>

#define VOCAB 8192
#define DIM 64
#define NQ 32768
#define CHUNK 64                    // centroids staged per LDS buffer
#define THREADS 256
#define QPB 128                     // queries per block (32 per wave)

typedef __attribute__((ext_vector_type(8))) _Float16 half8;
typedef __attribute__((ext_vector_type(4))) float f32x4;

#define LO_SCALE 4096.0f
#define LO_INV   2.44140625e-4f     // 1/4096

// ---------------- c2h[c] = -0.5 * ||vocab[c]||^2 ----------------
__global__ __launch_bounds__(256) void c2_kernel(const float* __restrict__ vocab,
                                                 float* __restrict__ c2h) {
    int c = blockIdx.x * 256 + threadIdx.x;
    const float4* row = (const float4*)(vocab + (size_t)c * DIM);
    float a0 = 0.f, a1 = 0.f, a2 = 0.f, a3 = 0.f;
#pragma unroll
    for (int k = 0; k < DIM / 4; ++k) {
        float4 v = row[k];
        a0 = fmaf(v.x, v.x, a0); a1 = fmaf(v.y, v.y, a1);
        a2 = fmaf(v.z, v.z, a2); a3 = fmaf(v.w, v.w, a3);
    }
    c2h[c] = -0.5f * ((a0 + a1) + (a2 + a3));
}

// ---------------- split fp32 -> f16 hi + f16 lo*4096 ----------------
__global__ __launch_bounds__(256) void split_kernel(const float* __restrict__ src,
                                                    _Float16* __restrict__ hi,
                                                    _Float16* __restrict__ lo) {
    int t = blockIdx.x * 256 + threadIdx.x;     // one thread per 8 elements
    const float4* s = (const float4*)(src + (size_t)t * 8);
    float4 f0 = s[0], f1 = s[1];
    float x[8] = {f0.x, f0.y, f0.z, f0.w, f1.x, f1.y, f1.z, f1.w};
    half8 h, l;
#pragma unroll
    for (int j = 0; j < 8; ++j) {
        _Float16 hh = (_Float16)x[j];
        h[j] = hh;
        l[j] = (_Float16)((x[j] - (float)hh) * LO_SCALE);   // scaled lo: stays normal
    }
    *(half8*)(hi + (size_t)t * 8) = h;
    *(half8*)(lo + (size_t)t * 8) = l;
}

// async global->LDS, 16B per lane, LDS dest = uniform base + lane*16 (implicit)
__device__ __forceinline__ void gload_lds(const _Float16* g, void* lds_dst) {
    __builtin_amdgcn_global_load_lds(
        (const __attribute__((address_space(1))) void*)g,
        (__attribute__((address_space(3))) void*)lds_dst, 16, 0, 0);
}

// ---------------- main: MFMA GEMM + fused argmin (argmax of dot - c2/2) ----------------
// A = patches (M=queries), B = vocab (N=centroids), mfma_f32_16x16x32_f16.
// C layout: col = lane&15 (centroid), row = (lane>>4)*4+reg (query).
// LDS tile [64 rows][8 x 16B], XOR-swizzled via pre-swizzled global source (m173/T2).
//
// OCCUPANCY NOTE (r4 post-mortem): on this toolchain __launch_bounds__'s 2nd
// arg acts as an effective waves/EU CAP (occupancy tracked it exactly: ~20% at
// 2, ~36% at 4). So we must declare 4 — but at 4 the unified VGPR+AGPR budget
// is 128, and the old 32-query/wave tile needed ~132 -> allocator collapsed to
// 64+64 and spilled A-frags (r3: FETCH 1.5GB). Fix: 32 queries/wave (t=2),
// ~100 regs total, fits 128 with no spill AND 4 waves/SIMD.
template <int NSLICE>
__global__ __launch_bounds__(THREADS, 4)
void argmin_mfma(const float* __restrict__ patches,
                 const _Float16* __restrict__ vhi,
                 const _Float16* __restrict__ vlo,
                 const float* __restrict__ c2g,     // holds -0.5*||c||^2
                 float* __restrict__ ws_best,
                 int*   __restrict__ ws_idx) {
    constexpr int CSLICE = VOCAB / NSLICE;
    constexpr int NCHUNK = CSLICE / CHUNK;
    __shared__ __align__(16) char smem[2 * 16384];   // [buf][hi 8KB | lo 8KB]

    const int tid   = threadIdx.x;
    const int lane  = tid & 63;
    const int w     = tid >> 6;                     // wave 0..3
    const int slice = blockIdx.x & (NSLICE - 1);    // bid%8 == XCD: 1 slice per XCD L2
    const int qg    = blockIdx.x / NSLICE;
    const int qbase = qg * QPB + w * 32;            // this wave's 32 queries
    const int cbase = slice * CSLICE;

    // ---- load + split this wave's A fragments (queries) into registers ----
    const int arow = lane & 15;                 // query row within 16-tile
    const int akc  = lane >> 4;                 // k-chunk 0..3 (8 elems each)
    half8 Ah[2][2], Al[2][2];
#pragma unroll
    for (int t = 0; t < 2; ++t)
#pragma unroll
        for (int ks = 0; ks < 2; ++ks) {
            const float* p = patches + (size_t)(qbase + t * 16 + arow) * DIM
                           + ks * 32 + akc * 8;
            float4 f0 = *(const float4*)p;
            float4 f1 = *(const float4*)(p + 4);
            float x[8] = {f0.x, f0.y, f0.z, f0.w, f1.x, f1.y, f1.z, f1.w};
            half8 h, l;
#pragma unroll
            for (int j = 0; j < 8; ++j) {
                _Float16 hh = (_Float16)x[j];
                h[j] = hh;
                l[j] = (_Float16)((x[j] - (float)hh) * LO_SCALE);
            }
            Ah[t][ks] = h; Al[t][ks] = l;
        }

    // staging source offset (elems): row = (lane>>3), col16' = (lane&7)^(lane>>3)
    const int s_srcoff = ((lane >> 3) * DIM) + (((lane & 7) ^ (lane >> 3)) * 8);
    // frag ds_read byte offsets: row fr, swizzled k-chunk
    const int fr = lane & 15;
    const int fx = fr & 7;
    const int b_off0 = fr * 128 + (((0 * 4 + akc) ^ fx) * 16);   // kstep 0
    const int b_off1 = fr * 128 + (((1 * 4 + akc) ^ fx) * 16);   // kstep 1

    float best[2][4];
    int   bidx[2][4];
#pragma unroll
    for (int t = 0; t < 2; ++t)
#pragma unroll
        for (int j = 0; j < 4; ++j) { best[t][j] = -FLT_MAX; bidx[t][j] = 0; }

    // ---- stage chunk 0 ----
    {
        const size_t crow = (size_t)cbase * DIM;
#pragma unroll
        for (int j = 0; j < 2; ++j) {
            int r0 = (w + 4 * j) * 8;           // 8 rows = 1KB per instr
            gload_lds(vhi + crow + (size_t)r0 * DIM + s_srcoff, smem + r0 * 128);
            gload_lds(vlo + crow + (size_t)r0 * DIM + s_srcoff, smem + 8192 + r0 * 128);
        }
    }
    __syncthreads();

    for (int ch = 0; ch < NCHUNK; ++ch) {
        const int cur = ch & 1;
        if (ch + 1 < NCHUNK) {                  // prefetch next chunk into other buffer
            const size_t crow = (size_t)(cbase + (ch + 1) * CHUNK) * DIM;
            char* dst = smem + (cur ^ 1) * 16384;
#pragma unroll
            for (int j = 0; j < 2; ++j) {
                int r0 = (w + 4 * j) * 8;
                gload_lds(vhi + crow + (size_t)r0 * DIM + s_srcoff, dst + r0 * 128);
                gload_lds(vlo + crow + (size_t)r0 * DIM + s_srcoff, dst + 8192 + r0 * 128);
            }
        }
        const char* hib = smem + cur * 16384;
        const char* lob = hib + 8192;
        const int cb = cbase + ch * CHUNK;

#pragma unroll
        for (int nt = 0; nt < 4; ++nt) {
            const int rt = nt * 16;
            half8 Bh0 = *(const half8*)(hib + rt * 128 + b_off0);
            half8 Bh1 = *(const half8*)(hib + rt * 128 + b_off1);
            half8 Bl0 = *(const half8*)(lob + rt * 128 + b_off0);
            half8 Bl1 = *(const half8*)(lob + rt * 128 + b_off1);
            const float c2h = c2g[cb + rt + fr];    // -0.5*||c||^2, this lane's col
            const int  cidx = cb + rt + fr;
#pragma unroll
            for (int t = 0; t < 2; ++t) {
                f32x4 am = {c2h, c2h, c2h, c2h};    // hi*hi, seeded with -c2/2
                f32x4 al = {0.f, 0.f, 0.f, 0.f};    // cross terms, scale 4096
                am = __builtin_amdgcn_mfma_f32_16x16x32_f16(Ah[t][0], Bh0, am, 0, 0, 0);
                am = __builtin_amdgcn_mfma_f32_16x16x32_f16(Ah[t][1], Bh1, am, 0, 0, 0);
                al = __builtin_amdgcn_mfma_f32_16x16x32_f16(Ah[t][0], Bl0, al, 0, 0, 0);
                al = __builtin_amdgcn_mfma_f32_16x16x32_f16(Ah[t][1], Bl1, al, 0, 0, 0);
                al = __builtin_amdgcn_mfma_f32_16x16x32_f16(Al[t][0], Bh0, al, 0, 0, 0);
                al = __builtin_amdgcn_mfma_f32_16x16x32_f16(Al[t][1], Bh1, al, 0, 0, 0);
#pragma unroll
                for (int j = 0; j < 4; ++j) {
                    float val = fmaf(al[j], LO_INV, am[j]);     // dot - c2/2
                    // argmax == argmin of distance; strict > keeps FIRST (lowest c) on ties
                    if (val > best[t][j]) { best[t][j] = val; bidx[t][j] = cidx; }
                }
            }
        }
        __syncthreads();    // drains prefetch + guards buffer reuse
    }

    // ---- butterfly argmax-merge across the 16 column-lanes of each row-group ----
#pragma unroll
    for (int t = 0; t < 2; ++t)
#pragma unroll
        for (int j = 0; j < 4; ++j) {
            float b = best[t][j]; int bi = bidx[t][j];
#pragma unroll
            for (int d = 1; d < 16; d <<= 1) {
                float ob = __shfl_xor(b, d, 64);
                int   oi = __shfl_xor(bi, d, 64);
                if (ob > b || (ob == b && oi < bi)) { b = ob; bi = oi; }
            }
            best[t][j] = b; bidx[t][j] = bi;
        }

    if ((lane & 15) == 0) {
        const int rg = lane >> 4;
#pragma unroll
        for (int t = 0; t < 2; ++t)
#pragma unroll
            for (int j = 0; j < 4; ++j) {
                int q = qbase + t * 16 + rg * 4 + j;
                ws_best[(size_t)slice * NQ + q] = best[t][j];
                ws_idx [(size_t)slice * NQ + q] = bidx[t][j];
            }
    }
}

// ---------------- merge slices (max of val, lower index on ties) ----------------
template <int NSLICE>
__global__ __launch_bounds__(256) void merge_kernel(const float* __restrict__ ws_best,
                                                    const int* __restrict__ ws_idx,
                                                    int* __restrict__ out) {
    int q = blockIdx.x * 256 + threadIdx.x;
    float b = ws_best[q]; int bi = ws_idx[q];
#pragma unroll
    for (int s = 1; s < NSLICE; ++s) {
        float v = ws_best[(size_t)s * NQ + q];
        int  vi = ws_idx[(size_t)s * NQ + q];
        if (v > b || (v == b && vi < bi)) { b = v; bi = vi; }
    }
    out[q] = bi;
}

extern "C" void kernel_launch(void* const* d_in, const int* in_sizes, int n_in,
                              void* d_out, int out_size, void* d_ws, size_t ws_size,
                              hipStream_t stream) {
    const float* patches = (const float*)d_in[0];   // [32768][64] fp32
    const float* vocab   = (const float*)d_in[1];   // [8192][64] fp32
    char* ws = (char*)d_ws;
    float*    c2    = (float*)ws;                                   // 32 KB
    _Float16* vhi   = (_Float16*)(ws + 32768);                      // 1 MB
    _Float16* vlo   = (_Float16*)(ws + 32768 + 1048576);            // 1 MB
    float*    wbest = (float*)(ws + 32768 + 2097152);
    int* out = (int*)d_out;

    c2_kernel   <<<VOCAB / 256, 256, 0, stream>>>(vocab, c2);
    split_kernel<<<(VOCAB * DIM / 8) / 256, 256, 0, stream>>>(vocab, vhi, vlo);

    // ws need for NSLICE=8: 32KB + 2MB + 8*32768*8 = ~4.3 MB
    const size_t base = 32768 + 2097152;
    if (ws_size >= base + (size_t)8 * NQ * 8) {
        int* widx = (int*)(ws + base + (size_t)8 * NQ * 4);
        argmin_mfma<8><<<(NQ / QPB) * 8, THREADS, 0, stream>>>(patches, vhi, vlo, c2, wbest, widx);
        merge_kernel<8><<<NQ / 256, 256, 0, stream>>>(wbest, widx, out);
    } else {
        int* widx = (int*)(ws + base + (size_t)4 * NQ * 4);
        argmin_mfma<4><<<(NQ / QPB) * 4, THREADS, 0, stream>>>(patches, vhi, vlo, c2, wbest, widx);
        merge_kernel<4><<<NQ / 256, 256, 0, stream>>>(wbest, widx, out);
    }
}

// Round 6
// 183.761 us; speedup vs baseline: 1.1802x; 1.1802x over previous
//
#include <hip/hip_runtime.h>
#include <float.h>

#define VOCAB 8192
#define DIM 64
#define NQ 32768
#define THREADS 256
#define QPB 256                     // queries per block (64 per wave, t=4)

typedef __attribute__((ext_vector_type(8))) _Float16 half8;
typedef __attribute__((ext_vector_type(4))) float f32x4;

#define LO_SCALE 4096.0f
#define LO_INV   2.44140625e-4f     // 1/4096

// ---------------- c2h[c] = -0.5 * ||vocab[c]||^2 ----------------
__global__ __launch_bounds__(256) void c2_kernel(const float* __restrict__ vocab,
                                                 float* __restrict__ c2h) {
    int c = blockIdx.x * 256 + threadIdx.x;
    const float4* row = (const float4*)(vocab + (size_t)c * DIM);
    float a0 = 0.f, a1 = 0.f, a2 = 0.f, a3 = 0.f;
#pragma unroll
    for (int k = 0; k < DIM / 4; ++k) {
        float4 v = row[k];
        a0 = fmaf(v.x, v.x, a0); a1 = fmaf(v.y, v.y, a1);
        a2 = fmaf(v.z, v.z, a2); a3 = fmaf(v.w, v.w, a3);
    }
    c2h[c] = -0.5f * ((a0 + a1) + (a2 + a3));
}

// ---------------- split fp32 -> f16 hi + f16 lo*4096 ----------------
__global__ __launch_bounds__(256) void split_kernel(const float* __restrict__ src,
                                                    _Float16* __restrict__ hi,
                                                    _Float16* __restrict__ lo) {
    int t = blockIdx.x * 256 + threadIdx.x;     // one thread per 8 elements
    const float4* s = (const float4*)(src + (size_t)t * 8);
    float4 f0 = s[0], f1 = s[1];
    float x[8] = {f0.x, f0.y, f0.z, f0.w, f1.x, f1.y, f1.z, f1.w};
    half8 h, l;
#pragma unroll
    for (int j = 0; j < 8; ++j) {
        _Float16 hh = (_Float16)x[j];
        h[j] = hh;
        l[j] = (_Float16)((x[j] - (float)hh) * LO_SCALE);   // scaled lo: stays normal
    }
    *(half8*)(hi + (size_t)t * 8) = h;
    *(half8*)(lo + (size_t)t * 8) = l;
}

// ---------------- main: barrier-free MFMA GEMM + fused argmin ----------------
// r5 post-mortem: the LDS double-buffer + __syncthreads-per-chunk structure IS
// the ~40% MfmaUtil ceiling (m97 barrier-drain), and occupancy hints either
// don't lift it (256,2) or trigger a 64/64 VGPR/AGPR split + spill (256,4).
// This version deletes LDS and all barriers: B (vocab hi/lo, 256KB per
// XCD-pinned slice) is L2-resident, so each wave loads its B fragments
// directly global->VGPR and free-runs; the compiler software-pipelines the
// loads under the 24 MFMAs/tile with no barrier forcing a vmcnt(0) drain.
// A frag: lane holds row lane&15, k=(lane>>4)*8+e.  B frag: col lane&15,
// same k.  C: col = lane&15 (centroid), row = (lane>>4)*4+reg (query).
template <int NSLICE>
__global__ __launch_bounds__(THREADS, 2)
void argmin_mfma(const float* __restrict__ patches,
                 const _Float16* __restrict__ vhi,
                 const _Float16* __restrict__ vlo,
                 const float* __restrict__ c2g,     // holds -0.5*||c||^2
                 float* __restrict__ ws_best,
                 int*   __restrict__ ws_idx) {
    constexpr int CSLICE = VOCAB / NSLICE;
    const int lane  = threadIdx.x & 63;
    const int w     = threadIdx.x >> 6;             // wave 0..3
    const int slice = blockIdx.x & (NSLICE - 1);    // bid%8 == XCD: slice per XCD L2
    const int qg    = blockIdx.x / NSLICE;
    const int qbase = qg * QPB + w * 64;            // this wave's 64 queries
    const int cbase = slice * CSLICE;

    // ---- load + split this wave's A fragments (queries) into registers ----
    const int arow = lane & 15;                 // query row within 16-tile
    const int akc  = lane >> 4;                 // k-chunk 0..3 (8 elems each)
    half8 Ah[4][2], Al[4][2];
#pragma unroll
    for (int t = 0; t < 4; ++t)
#pragma unroll
        for (int ks = 0; ks < 2; ++ks) {
            const float* p = patches + (size_t)(qbase + t * 16 + arow) * DIM
                           + ks * 32 + akc * 8;
            float4 f0 = *(const float4*)p;
            float4 f1 = *(const float4*)(p + 4);
            float x[8] = {f0.x, f0.y, f0.z, f0.w, f1.x, f1.y, f1.z, f1.w};
            half8 h, l;
#pragma unroll
            for (int j = 0; j < 8; ++j) {
                _Float16 hh = (_Float16)x[j];
                h[j] = hh;
                l[j] = (_Float16)((x[j] - (float)hh) * LO_SCALE);
            }
            Ah[t][ks] = h; Al[t][ks] = l;
        }

    // per-lane byte offset inside a 16-centroid B tile:
    // row = fr (this lane's centroid), kstep0 bytes [akc*16), kstep1 +64
    const int  fr   = lane & 15;
    const int  boff = fr * 128 + akc * 16;
    const char* hptr = (const char*)vhi + (size_t)cbase * 128 + boff;
    const char* lptr = (const char*)vlo + (size_t)cbase * 128 + boff;

    float best[4][4];
    int   bidx[4][4];
#pragma unroll
    for (int t = 0; t < 4; ++t)
#pragma unroll
        for (int j = 0; j < 4; ++j) { best[t][j] = -FLT_MAX; bidx[t][j] = 0; }

    // ---- main loop: one 16-centroid tile per iteration, no barriers ----
#pragma unroll 2
    for (int ct = 0; ct < CSLICE / 16; ++ct) {
        const char* hb = hptr + (size_t)ct * 2048;      // 16 rows * 128 B
        const char* lb = lptr + (size_t)ct * 2048;
        half8 Bh0 = *(const half8*)(hb);
        half8 Bh1 = *(const half8*)(hb + 64);
        half8 Bl0 = *(const half8*)(lb);
        half8 Bl1 = *(const half8*)(lb + 64);
        const int   cidx = cbase + ct * 16 + fr;        // this lane's centroid col
        const float c2h  = c2g[cidx];                   // -0.5*||c||^2
#pragma unroll
        for (int t = 0; t < 4; ++t) {
            f32x4 am = {c2h, c2h, c2h, c2h};    // hi*hi stream, seeded with -c2/2
            f32x4 al = {0.f, 0.f, 0.f, 0.f};    // cross terms, scale 4096
            am = __builtin_amdgcn_mfma_f32_16x16x32_f16(Ah[t][0], Bh0, am, 0, 0, 0);
            am = __builtin_amdgcn_mfma_f32_16x16x32_f16(Ah[t][1], Bh1, am, 0, 0, 0);
            al = __builtin_amdgcn_mfma_f32_16x16x32_f16(Ah[t][0], Bl0, al, 0, 0, 0);
            al = __builtin_amdgcn_mfma_f32_16x16x32_f16(Ah[t][1], Bl1, al, 0, 0, 0);
            al = __builtin_amdgcn_mfma_f32_16x16x32_f16(Al[t][0], Bh0, al, 0, 0, 0);
            al = __builtin_amdgcn_mfma_f32_16x16x32_f16(Al[t][1], Bh1, al, 0, 0, 0);
#pragma unroll
            for (int j = 0; j < 4; ++j) {
                float val = fmaf(al[j], LO_INV, am[j]);     // dot - c2/2
                // argmax == argmin of distance; strict > keeps FIRST (lowest c) on ties
                if (val > best[t][j]) { best[t][j] = val; bidx[t][j] = cidx; }
            }
        }
    }

    // ---- butterfly argmax-merge across the 16 column-lanes of each row-group ----
#pragma unroll
    for (int t = 0; t < 4; ++t)
#pragma unroll
        for (int j = 0; j < 4; ++j) {
            float b = best[t][j]; int bi = bidx[t][j];
#pragma unroll
            for (int d = 1; d < 16; d <<= 1) {
                float ob = __shfl_xor(b, d, 64);
                int   oi = __shfl_xor(bi, d, 64);
                if (ob > b || (ob == b && oi < bi)) { b = ob; bi = oi; }
            }
            best[t][j] = b; bidx[t][j] = bi;
        }

    if ((lane & 15) == 0) {
        const int rg = lane >> 4;
#pragma unroll
        for (int t = 0; t < 4; ++t)
#pragma unroll
            for (int j = 0; j < 4; ++j) {
                int q = qbase + t * 16 + rg * 4 + j;
                ws_best[(size_t)slice * NQ + q] = best[t][j];
                ws_idx [(size_t)slice * NQ + q] = bidx[t][j];
            }
    }
}

// ---------------- merge slices (max of val, lower index on ties) ----------------
template <int NSLICE>
__global__ __launch_bounds__(256) void merge_kernel(const float* __restrict__ ws_best,
                                                    const int* __restrict__ ws_idx,
                                                    int* __restrict__ out) {
    int q = blockIdx.x * 256 + threadIdx.x;
    float b = ws_best[q]; int bi = ws_idx[q];
#pragma unroll
    for (int s = 1; s < NSLICE; ++s) {
        float v = ws_best[(size_t)s * NQ + q];
        int  vi = ws_idx[(size_t)s * NQ + q];
        if (v > b || (v == b && vi < bi)) { b = v; bi = vi; }
    }
    out[q] = bi;
}

extern "C" void kernel_launch(void* const* d_in, const int* in_sizes, int n_in,
                              void* d_out, int out_size, void* d_ws, size_t ws_size,
                              hipStream_t stream) {
    const float* patches = (const float*)d_in[0];   // [32768][64] fp32
    const float* vocab   = (const float*)d_in[1];   // [8192][64] fp32
    char* ws = (char*)d_ws;
    float*    c2    = (float*)ws;                                   // 32 KB
    _Float16* vhi   = (_Float16*)(ws + 32768);                      // 1 MB
    _Float16* vlo   = (_Float16*)(ws + 32768 + 1048576);            // 1 MB
    float*    wbest = (float*)(ws + 32768 + 2097152);
    int* out = (int*)d_out;

    c2_kernel   <<<VOCAB / 256, 256, 0, stream>>>(vocab, c2);
    split_kernel<<<(VOCAB * DIM / 8) / 256, 256, 0, stream>>>(vocab, vhi, vlo);

    // ws need for NSLICE=8: 32KB + 2MB + 8*32768*8 = ~4.3 MB
    const size_t base = 32768 + 2097152;
    if (ws_size >= base + (size_t)8 * NQ * 8) {
        int* widx = (int*)(ws + base + (size_t)8 * NQ * 4);
        argmin_mfma<8><<<(NQ / QPB) * 8, THREADS, 0, stream>>>(patches, vhi, vlo, c2, wbest, widx);
        merge_kernel<8><<<NQ / 256, 256, 0, stream>>>(wbest, widx, out);
    } else {
        int* widx = (int*)(ws + base + (size_t)4 * NQ * 4);
        argmin_mfma<4><<<(NQ / QPB) * 4, THREADS, 0, stream>>>(patches, vhi, vlo, c2, wbest, widx);
        merge_kernel<4><<<NQ / 256, 256, 0, stream>>>(wbest, widx, out);
    }
}

// Round 7
// 169.509 us; speedup vs baseline: 1.2795x; 1.0841x over previous
//
#include <hip/hip_runtime.h>
#include <float.h>

#define VOCAB 8192
#define DIM 64
#define NQ 32768
#define CHUNK 64                    // centroids staged per LDS buffer
#define THREADS 256
#define QPB 256                     // queries per block (64 per wave, t=4)

typedef __attribute__((ext_vector_type(8))) _Float16 half8;
typedef __attribute__((ext_vector_type(4))) float f32x4;

#define LO_SCALE 4096.0f
#define LO_INV   2.44140625e-4f     // 1/4096

// ---------------- c2h[c] = -0.5 * ||vocab[c]||^2 ----------------
__global__ __launch_bounds__(256) void c2_kernel(const float* __restrict__ vocab,
                                                 float* __restrict__ c2h) {
    int c = blockIdx.x * 256 + threadIdx.x;
    const float4* row = (const float4*)(vocab + (size_t)c * DIM);
    float a0 = 0.f, a1 = 0.f, a2 = 0.f, a3 = 0.f;
#pragma unroll
    for (int k = 0; k < DIM / 4; ++k) {
        float4 v = row[k];
        a0 = fmaf(v.x, v.x, a0); a1 = fmaf(v.y, v.y, a1);
        a2 = fmaf(v.z, v.z, a2); a3 = fmaf(v.w, v.w, a3);
    }
    c2h[c] = -0.5f * ((a0 + a1) + (a2 + a3));
}

// ---------------- split fp32 -> f16 hi + f16 lo*4096 ----------------
__global__ __launch_bounds__(256) void split_kernel(const float* __restrict__ src,
                                                    _Float16* __restrict__ hi,
                                                    _Float16* __restrict__ lo) {
    int t = blockIdx.x * 256 + threadIdx.x;     // one thread per 8 elements
    const float4* s = (const float4*)(src + (size_t)t * 8);
    float4 f0 = s[0], f1 = s[1];
    float x[8] = {f0.x, f0.y, f0.z, f0.w, f1.x, f1.y, f1.z, f1.w};
    half8 h, l;
#pragma unroll
    for (int j = 0; j < 8; ++j) {
        _Float16 hh = (_Float16)x[j];
        h[j] = hh;
        l[j] = (_Float16)((x[j] - (float)hh) * LO_SCALE);   // scaled lo: stays normal
    }
    *(half8*)(hi + (size_t)t * 8) = h;
    *(half8*)(lo + (size_t)t * 8) = l;
}

// async global->LDS, 16B per lane, LDS dest = uniform base + lane*16 (implicit)
__device__ __forceinline__ void gload_lds(const _Float16* g, void* lds_dst) {
    __builtin_amdgcn_global_load_lds(
        (const __attribute__((address_space(1))) void*)g,
        (__attribute__((address_space(3))) void*)lds_dst, 16, 0, 0);
}

// ---------------- main: MFMA GEMM + fused argmin (argmax of dot - c2/2) ----------------
// Structure = r2's proven kernel (absmax 0, no spill, 0 bank conflicts).
//
// LAUNCH-BOUNDS POST-MORTEM (r2-r6): on this toolchain the 2nd arg acts as a
// hard waves/EU CAP (occupancy ~20% at 2 across three different grids; ~36%
// at 4) and at 4 it forces a 64/64 arch/acc register split that spills any
// tile >= ~80 regs (r3/r5: FETCH 0.3-1.5 GB of scratch traffic). So: NO
// second arg. The allocator then maximizes occupancy without spilling ->
// ~128 VGPR = 4 waves/SIMD; residency becomes HW-limited (VGPR: 4 blocks/CU,
// LDS 32KB: 5) instead of hint-capped. Grid 1024 = exactly 4 blocks/CU.
template <int NSLICE>
__global__ __launch_bounds__(THREADS)
void argmin_mfma(const float* __restrict__ patches,
                 const _Float16* __restrict__ vhi,
                 const _Float16* __restrict__ vlo,
                 const float* __restrict__ c2g,     // holds -0.5*||c||^2
                 float* __restrict__ ws_best,
                 int*   __restrict__ ws_idx) {
    constexpr int CSLICE = VOCAB / NSLICE;
    constexpr int NCHUNK = CSLICE / CHUNK;
    __shared__ __align__(16) char smem[2 * 16384];   // [buf][hi 8KB | lo 8KB]

    const int tid   = threadIdx.x;
    const int lane  = tid & 63;
    const int w     = tid >> 6;                     // wave 0..3
    const int slice = blockIdx.x & (NSLICE - 1);    // bid%8 == XCD: slice per XCD L2
    const int qg    = blockIdx.x / NSLICE;
    const int qbase = qg * QPB + w * 64;            // this wave's 64 queries
    const int cbase = slice * CSLICE;

    // ---- load + split this wave's A fragments (queries) into registers ----
    const int arow = lane & 15;                 // query row within 16-tile
    const int akc  = lane >> 4;                 // k-chunk 0..3 (8 elems each)
    half8 Ah[4][2], Al[4][2];
#pragma unroll
    for (int t = 0; t < 4; ++t)
#pragma unroll
        for (int ks = 0; ks < 2; ++ks) {
            const float* p = patches + (size_t)(qbase + t * 16 + arow) * DIM
                           + ks * 32 + akc * 8;
            float4 f0 = *(const float4*)p;
            float4 f1 = *(const float4*)(p + 4);
            float x[8] = {f0.x, f0.y, f0.z, f0.w, f1.x, f1.y, f1.z, f1.w};
            half8 h, l;
#pragma unroll
            for (int j = 0; j < 8; ++j) {
                _Float16 hh = (_Float16)x[j];
                h[j] = hh;
                l[j] = (_Float16)((x[j] - (float)hh) * LO_SCALE);
            }
            Ah[t][ks] = h; Al[t][ks] = l;
        }

    // staging source offset (elems): row = (lane>>3), col16' = (lane&7)^(lane>>3)
    const int s_srcoff = ((lane >> 3) * DIM) + (((lane & 7) ^ (lane >> 3)) * 8);
    // frag ds_read byte offsets: row fr, swizzled k-chunk
    const int fr = lane & 15;
    const int fx = fr & 7;
    const int b_off0 = fr * 128 + (((0 * 4 + akc) ^ fx) * 16);   // kstep 0
    const int b_off1 = fr * 128 + (((1 * 4 + akc) ^ fx) * 16);   // kstep 1

    float best[4][4];
    int   bidx[4][4];
#pragma unroll
    for (int t = 0; t < 4; ++t)
#pragma unroll
        for (int j = 0; j < 4; ++j) { best[t][j] = -FLT_MAX; bidx[t][j] = 0; }

    // ---- stage chunk 0 ----
    {
        const size_t crow = (size_t)cbase * DIM;
#pragma unroll
        for (int j = 0; j < 2; ++j) {
            int r0 = (w + 4 * j) * 8;           // 8 rows = 1KB per instr
            gload_lds(vhi + crow + (size_t)r0 * DIM + s_srcoff, smem + r0 * 128);
            gload_lds(vlo + crow + (size_t)r0 * DIM + s_srcoff, smem + 8192 + r0 * 128);
        }
    }
    __syncthreads();

    for (int ch = 0; ch < NCHUNK; ++ch) {
        const int cur = ch & 1;
        if (ch + 1 < NCHUNK) {                  // prefetch next chunk into other buffer
            const size_t crow = (size_t)(cbase + (ch + 1) * CHUNK) * DIM;
            char* dst = smem + (cur ^ 1) * 16384;
#pragma unroll
            for (int j = 0; j < 2; ++j) {
                int r0 = (w + 4 * j) * 8;
                gload_lds(vhi + crow + (size_t)r0 * DIM + s_srcoff, dst + r0 * 128);
                gload_lds(vlo + crow + (size_t)r0 * DIM + s_srcoff, dst + 8192 + r0 * 128);
            }
        }
        const char* hib = smem + cur * 16384;
        const char* lob = hib + 8192;
        const int cb = cbase + ch * CHUNK;

#pragma unroll
        for (int nt = 0; nt < 4; ++nt) {
            const int rt = nt * 16;
            half8 Bh0 = *(const half8*)(hib + rt * 128 + b_off0);
            half8 Bh1 = *(const half8*)(hib + rt * 128 + b_off1);
            half8 Bl0 = *(const half8*)(lob + rt * 128 + b_off0);
            half8 Bl1 = *(const half8*)(lob + rt * 128 + b_off1);
            const float c2h = c2g[cb + rt + fr];    // -0.5*||c||^2, this lane's col
            const int  cidx = cb + rt + fr;
#pragma unroll
            for (int t = 0; t < 4; ++t) {
                f32x4 am = {c2h, c2h, c2h, c2h};    // hi*hi, seeded with -c2/2
                f32x4 al = {0.f, 0.f, 0.f, 0.f};    // cross terms, scale 4096
                am = __builtin_amdgcn_mfma_f32_16x16x32_f16(Ah[t][0], Bh0, am, 0, 0, 0);
                am = __builtin_amdgcn_mfma_f32_16x16x32_f16(Ah[t][1], Bh1, am, 0, 0, 0);
                al = __builtin_amdgcn_mfma_f32_16x16x32_f16(Ah[t][0], Bl0, al, 0, 0, 0);
                al = __builtin_amdgcn_mfma_f32_16x16x32_f16(Ah[t][1], Bl1, al, 0, 0, 0);
                al = __builtin_amdgcn_mfma_f32_16x16x32_f16(Al[t][0], Bh0, al, 0, 0, 0);
                al = __builtin_amdgcn_mfma_f32_16x16x32_f16(Al[t][1], Bh1, al, 0, 0, 0);
#pragma unroll
                for (int j = 0; j < 4; ++j) {
                    float val = fmaf(al[j], LO_INV, am[j]);     // dot - c2/2
                    // argmax == argmin of distance; strict > keeps FIRST (lowest c) on ties
                    if (val > best[t][j]) { best[t][j] = val; bidx[t][j] = cidx; }
                }
            }
        }
        __syncthreads();    // drains prefetch + guards buffer reuse
    }

    // ---- butterfly argmax-merge across the 16 column-lanes of each row-group ----
#pragma unroll
    for (int t = 0; t < 4; ++t)
#pragma unroll
        for (int j = 0; j < 4; ++j) {
            float b = best[t][j]; int bi = bidx[t][j];
#pragma unroll
            for (int d = 1; d < 16; d <<= 1) {
                float ob = __shfl_xor(b, d, 64);
                int   oi = __shfl_xor(bi, d, 64);
                if (ob > b || (ob == b && oi < bi)) { b = ob; bi = oi; }
            }
            best[t][j] = b; bidx[t][j] = bi;
        }

    if ((lane & 15) == 0) {
        const int rg = lane >> 4;
#pragma unroll
        for (int t = 0; t < 4; ++t)
#pragma unroll
            for (int j = 0; j < 4; ++j) {
                int q = qbase + t * 16 + rg * 4 + j;
                ws_best[(size_t)slice * NQ + q] = best[t][j];
                ws_idx [(size_t)slice * NQ + q] = bidx[t][j];
            }
    }
}

// ---------------- merge slices (max of val, lower index on ties) ----------------
template <int NSLICE>
__global__ __launch_bounds__(256) void merge_kernel(const float* __restrict__ ws_best,
                                                    const int* __restrict__ ws_idx,
                                                    int* __restrict__ out) {
    int q = blockIdx.x * 256 + threadIdx.x;
    float b = ws_best[q]; int bi = ws_idx[q];
#pragma unroll
    for (int s = 1; s < NSLICE; ++s) {
        float v = ws_best[(size_t)s * NQ + q];
        int  vi = ws_idx[(size_t)s * NQ + q];
        if (v > b || (v == b && vi < bi)) { b = v; bi = vi; }
    }
    out[q] = bi;
}

extern "C" void kernel_launch(void* const* d_in, const int* in_sizes, int n_in,
                              void* d_out, int out_size, void* d_ws, size_t ws_size,
                              hipStream_t stream) {
    const float* patches = (const float*)d_in[0];   // [32768][64] fp32
    const float* vocab   = (const float*)d_in[1];   // [8192][64] fp32
    char* ws = (char*)d_ws;
    float*    c2    = (float*)ws;                                   // 32 KB
    _Float16* vhi   = (_Float16*)(ws + 32768);                      // 1 MB
    _Float16* vlo   = (_Float16*)(ws + 32768 + 1048576);            // 1 MB
    float*    wbest = (float*)(ws + 32768 + 2097152);
    int* out = (int*)d_out;

    c2_kernel   <<<VOCAB / 256, 256, 0, stream>>>(vocab, c2);
    split_kernel<<<(VOCAB * DIM / 8) / 256, 256, 0, stream>>>(vocab, vhi, vlo);

    // ws need for NSLICE=8: 32KB + 2MB + 8*32768*8 = ~4.3 MB
    const size_t base = 32768 + 2097152;
    if (ws_size >= base + (size_t)8 * NQ * 8) {
        int* widx = (int*)(ws + base + (size_t)8 * NQ * 4);
        argmin_mfma<8><<<(NQ / QPB) * 8, THREADS, 0, stream>>>(patches, vhi, vlo, c2, wbest, widx);
        merge_kernel<8><<<NQ / 256, 256, 0, stream>>>(wbest, widx, out);
    } else {
        int* widx = (int*)(ws + base + (size_t)4 * NQ * 4);
        argmin_mfma<4><<<(NQ / QPB) * 4, THREADS, 0, stream>>>(patches, vhi, vlo, c2, wbest, widx);
        merge_kernel<4><<<NQ / 256, 256, 0, stream>>>(wbest, widx, out);
    }
}

// Round 8
// 103.858 us; speedup vs baseline: 2.0882x; 1.6321x over previous
//
#include <hip/hip_runtime.h>
#include <float.h>

#define VOCAB 8192
#define DIM 64
#define NQ 32768
#define CHUNK 64                    // centroids staged per LDS buffer
#define THREADS 256
#define QPB 256                     // queries per block (64 per wave, t=4)
#define NSLICE 4

typedef __attribute__((ext_vector_type(8))) _Float16 half8;
typedef __attribute__((ext_vector_type(4))) float f32x4;

#define LO_SCALE 4096.0f
#define LO_INV   2.44140625e-4f     // 1/4096

// ---------------- c2h[c] = -0.5 * ||vocab[c]||^2 ----------------
__global__ __launch_bounds__(256) void c2_kernel(const float* __restrict__ vocab,
                                                 float* __restrict__ c2h) {
    int c = blockIdx.x * 256 + threadIdx.x;
    const float4* row = (const float4*)(vocab + (size_t)c * DIM);
    float a0 = 0.f, a1 = 0.f, a2 = 0.f, a3 = 0.f;
#pragma unroll
    for (int k = 0; k < DIM / 4; ++k) {
        float4 v = row[k];
        a0 = fmaf(v.x, v.x, a0); a1 = fmaf(v.y, v.y, a1);
        a2 = fmaf(v.z, v.z, a2); a3 = fmaf(v.w, v.w, a3);
    }
    c2h[c] = -0.5f * ((a0 + a1) + (a2 + a3));
}

// ---------------- split fp32 -> f16 hi + f16 lo*4096 ----------------
__global__ __launch_bounds__(256) void split_kernel(const float* __restrict__ src,
                                                    _Float16* __restrict__ hi,
                                                    _Float16* __restrict__ lo) {
    int t = blockIdx.x * 256 + threadIdx.x;     // one thread per 8 elements
    const float4* s = (const float4*)(src + (size_t)t * 8);
    float4 f0 = s[0], f1 = s[1];
    float x[8] = {f0.x, f0.y, f0.z, f0.w, f1.x, f1.y, f1.z, f1.w};
    half8 h, l;
#pragma unroll
    for (int j = 0; j < 8; ++j) {
        _Float16 hh = (_Float16)x[j];
        h[j] = hh;
        l[j] = (_Float16)((x[j] - (float)hh) * LO_SCALE);   // scaled lo: stays normal
    }
    *(half8*)(hi + (size_t)t * 8) = h;
    *(half8*)(lo + (size_t)t * 8) = l;
}

// async global->LDS; LDS dest = uniform base + lane*size (implicit). size literal.
__device__ __forceinline__ void gload_lds16(const void* g, void* lds_dst) {
    __builtin_amdgcn_global_load_lds(
        (const __attribute__((address_space(1))) void*)g,
        (__attribute__((address_space(3))) void*)lds_dst, 16, 0, 0);
}
__device__ __forceinline__ void gload_lds4(const void* g, void* lds_dst) {
    __builtin_amdgcn_global_load_lds(
        (const __attribute__((address_space(1))) void*)g,
        (__attribute__((address_space(3))) void*)lds_dst, 4, 0, 0);
}

// ---------------- main: MFMA GEMM + fused argmin (argmax of dot - c2/2) ----------------
// Base = r2's proven kernel (124 VGPR no spill, absmax 0, 0 bank conflicts) at
// __launch_bounds__(256,2) — the only allocator setting that doesn't spill or
// bloat (r3/r5: (256,4) -> 64/64 split + spill; r7: no hint -> 160 VGPR).
//
// THIS ROUND (T4-lite): r2's __syncthreads per chunk = vmcnt(0)+lgkmcnt(0)
// drain of the just-issued prefetch (m97 stall). Replaced with raw s_barrier +
// counted s_waitcnt vmcnt(5): the next chunk's 5 staging loads stay in flight
// across the barrier. To keep the count exact, c2 is staged into LDS as the
// 5th gload_lds (no stray VMEM in the steady loop). setprio(1) wraps the MFMA
// clusters (T5): the 2 co-resident blocks/SIMD drift out of phase -> the CU
// scheduler can prefer the MFMA-issuing wave.
// Sync proof: begin-barrier (after own vmcnt(5)) => all waves' ch-loads
// landed before any ds_read of ch; end-barrier => all reads of buf[ch&1] done
// before iter ch+1 issues DMA that overwrites it. Both implied by r2's single
// barrier+full-drain, so no new race surface.
__global__ __launch_bounds__(THREADS, 2)
void argmin_mfma(const float* __restrict__ patches,
                 const _Float16* __restrict__ vhi,
                 const _Float16* __restrict__ vlo,
                 const float* __restrict__ c2g,     // holds -0.5*||c||^2
                 float* __restrict__ ws_best,
                 int*   __restrict__ ws_idx) {
    constexpr int CSLICE = VOCAB / NSLICE;
    constexpr int NCHUNK = CSLICE / CHUNK;
    // [buf0: hi 8K | lo 8K][buf1: hi 8K | lo 8K][c2 buf0 256B][c2 buf1 256B]
    __shared__ __align__(16) char smem[2 * 16384 + 2 * 256];

    const int tid   = threadIdx.x;
    const int lane  = tid & 63;
    const int w     = tid >> 6;                     // wave 0..3
    const int slice = blockIdx.x & (NSLICE - 1);    // XCD-aligned vocab slice
    const int qg    = blockIdx.x / NSLICE;
    const int qbase = qg * QPB + w * 64;            // this wave's 64 queries
    const int cbase = slice * CSLICE;

    // ---- load + split this wave's A fragments (queries) into registers ----
    const int arow = lane & 15;                 // query row within 16-tile
    const int akc  = lane >> 4;                 // k-chunk 0..3 (8 elems each)
    half8 Ah[4][2], Al[4][2];
#pragma unroll
    for (int t = 0; t < 4; ++t)
#pragma unroll
        for (int ks = 0; ks < 2; ++ks) {
            const float* p = patches + (size_t)(qbase + t * 16 + arow) * DIM
                           + ks * 32 + akc * 8;
            float4 f0 = *(const float4*)p;
            float4 f1 = *(const float4*)(p + 4);
            float x[8] = {f0.x, f0.y, f0.z, f0.w, f1.x, f1.y, f1.z, f1.w};
            half8 h, l;
#pragma unroll
            for (int j = 0; j < 8; ++j) {
                _Float16 hh = (_Float16)x[j];
                h[j] = hh;
                l[j] = (_Float16)((x[j] - (float)hh) * LO_SCALE);
            }
            Ah[t][ks] = h; Al[t][ks] = l;
        }

    // staging source offset (elems): row = (lane>>3), col16' = (lane&7)^(lane>>3)
    const int s_srcoff = ((lane >> 3) * DIM) + (((lane & 7) ^ (lane >> 3)) * 8);
    // frag ds_read byte offsets: row fr, swizzled k-chunk
    const int fr = lane & 15;
    const int fx = fr & 7;
    const int b_off0 = fr * 128 + (((0 * 4 + akc) ^ fx) * 16);   // kstep 0
    const int b_off1 = fr * 128 + (((1 * 4 + akc) ^ fx) * 16);   // kstep 1

    // stage chunk ch into buffer buf: 4x 1KB hi/lo + 256B c2 = 5 VMEM/wave
    auto stage = [&](int ch, int buf) {
        const size_t crow = (size_t)(cbase + ch * CHUNK) * DIM;
        char* dst = smem + buf * 16384;
#pragma unroll
        for (int j = 0; j < 2; ++j) {
            int r0 = (w + 4 * j) * 8;           // 8 rows = 1KB per instr
            gload_lds16(vhi + crow + (size_t)r0 * DIM + s_srcoff, dst + r0 * 128);
            gload_lds16(vlo + crow + (size_t)r0 * DIM + s_srcoff, dst + 8192 + r0 * 128);
        }
        // all 4 waves duplicate the same 256B c2 row (identical data, benign)
        gload_lds4(c2g + cbase + ch * CHUNK + lane, smem + 32768 + buf * 256);
    };

    float best[4][4];
    int   bidx[4][4];
#pragma unroll
    for (int t = 0; t < 4; ++t)
#pragma unroll
        for (int j = 0; j < 4; ++j) { best[t][j] = -FLT_MAX; bidx[t][j] = 0; }

    stage(0, 0);

    for (int ch = 0; ch < NCHUNK; ++ch) {
        const int cur = ch & 1;
        if (ch + 1 < NCHUNK) {
            stage(ch + 1, cur ^ 1);
            // own ch-loads done; ch+1's 5 stay in flight across the barrier
            asm volatile("s_waitcnt vmcnt(5)" ::: "memory");
        } else {
            asm volatile("s_waitcnt vmcnt(0)" ::: "memory");
        }
        __builtin_amdgcn_s_barrier();   // all waves' ch staging landed

        const char*  hib = smem + cur * 16384;
        const char*  lob = hib + 8192;
        const float* c2b = (const float*)(smem + 32768 + cur * 256);
        const int cb = cbase + ch * CHUNK;

#pragma unroll
        for (int nt = 0; nt < 4; ++nt) {
            const int rt = nt * 16;
            half8 Bh0 = *(const half8*)(hib + rt * 128 + b_off0);
            half8 Bh1 = *(const half8*)(hib + rt * 128 + b_off1);
            half8 Bl0 = *(const half8*)(lob + rt * 128 + b_off0);
            half8 Bl1 = *(const half8*)(lob + rt * 128 + b_off1);
            const float c2h = c2b[rt + fr];         // -0.5*||c||^2 (LDS)
            const int  cidx = cb + rt + fr;
            __builtin_amdgcn_s_setprio(1);
#pragma unroll
            for (int t = 0; t < 4; ++t) {
                f32x4 am = {c2h, c2h, c2h, c2h};    // hi*hi, seeded with -c2/2
                f32x4 al = {0.f, 0.f, 0.f, 0.f};    // cross terms, scale 4096
                am = __builtin_amdgcn_mfma_f32_16x16x32_f16(Ah[t][0], Bh0, am, 0, 0, 0);
                am = __builtin_amdgcn_mfma_f32_16x16x32_f16(Ah[t][1], Bh1, am, 0, 0, 0);
                al = __builtin_amdgcn_mfma_f32_16x16x32_f16(Ah[t][0], Bl0, al, 0, 0, 0);
                al = __builtin_amdgcn_mfma_f32_16x16x32_f16(Ah[t][1], Bl1, al, 0, 0, 0);
                al = __builtin_amdgcn_mfma_f32_16x16x32_f16(Al[t][0], Bh0, al, 0, 0, 0);
                al = __builtin_amdgcn_mfma_f32_16x16x32_f16(Al[t][1], Bh1, al, 0, 0, 0);
#pragma unroll
                for (int j = 0; j < 4; ++j) {
                    float val = fmaf(al[j], LO_INV, am[j]);     // dot - c2/2
                    // argmax == argmin of distance; strict > keeps FIRST (lowest c) on ties
                    if (val > best[t][j]) { best[t][j] = val; bidx[t][j] = cidx; }
                }
            }
            __builtin_amdgcn_s_setprio(0);
        }
        __builtin_amdgcn_s_barrier();   // all reads of buf[cur] done before overwrite
    }

    // ---- butterfly argmax-merge across the 16 column-lanes of each row-group ----
#pragma unroll
    for (int t = 0; t < 4; ++t)
#pragma unroll
        for (int j = 0; j < 4; ++j) {
            float b = best[t][j]; int bi = bidx[t][j];
#pragma unroll
            for (int d = 1; d < 16; d <<= 1) {
                float ob = __shfl_xor(b, d, 64);
                int   oi = __shfl_xor(bi, d, 64);
                if (ob > b || (ob == b && oi < bi)) { b = ob; bi = oi; }
            }
            best[t][j] = b; bidx[t][j] = bi;
        }

    if ((lane & 15) == 0) {
        const int rg = lane >> 4;
#pragma unroll
        for (int t = 0; t < 4; ++t)
#pragma unroll
            for (int j = 0; j < 4; ++j) {
                int q = qbase + t * 16 + rg * 4 + j;
                ws_best[(size_t)slice * NQ + q] = best[t][j];
                ws_idx [(size_t)slice * NQ + q] = bidx[t][j];
            }
    }
}

// ---------------- merge slices (max of val, lower index on ties) ----------------
__global__ __launch_bounds__(256) void merge_kernel(const float* __restrict__ ws_best,
                                                    const int* __restrict__ ws_idx,
                                                    int* __restrict__ out) {
    int q = blockIdx.x * 256 + threadIdx.x;
    float b = ws_best[q]; int bi = ws_idx[q];
#pragma unroll
    for (int s = 1; s < NSLICE; ++s) {
        float v = ws_best[(size_t)s * NQ + q];
        int  vi = ws_idx[(size_t)s * NQ + q];
        if (v > b || (v == b && vi < bi)) { b = v; bi = vi; }
    }
    out[q] = bi;
}

extern "C" void kernel_launch(void* const* d_in, const int* in_sizes, int n_in,
                              void* d_out, int out_size, void* d_ws, size_t ws_size,
                              hipStream_t stream) {
    const float* patches = (const float*)d_in[0];   // [32768][64] fp32
    const float* vocab   = (const float*)d_in[1];   // [8192][64] fp32
    char* ws = (char*)d_ws;
    float*    c2    = (float*)ws;                                   // 32 KB
    _Float16* vhi   = (_Float16*)(ws + 32768);                      // 1 MB
    _Float16* vlo   = (_Float16*)(ws + 32768 + 1048576);            // 1 MB
    float*    wbest = (float*)(ws + 32768 + 2097152);               // 512 KB
    int*      widx  = (int*)  (ws + 32768 + 2097152 + 524288);      // 512 KB
    int* out = (int*)d_out;

    c2_kernel   <<<VOCAB / 256, 256, 0, stream>>>(vocab, c2);
    split_kernel<<<(VOCAB * DIM / 8) / 256, 256, 0, stream>>>(vocab, vhi, vlo);
    argmin_mfma <<<(NQ / QPB) * NSLICE, THREADS, 0, stream>>>(patches, vhi, vlo, c2, wbest, widx);
    merge_kernel<<<NQ / 256, 256, 0, stream>>>(wbest, widx, out);
}